// Round 1
// 541.148 us; speedup vs baseline: 1.7607x; 1.7607x over previous
//
#include <hip/hip_runtime.h>
#include <hip/hip_fp16.h>

#define N_PIX 9216
#define CCH 256
#define W_ 96
#define H_ 96
#define BM 128
#define BN 128
#define BK 16
#define TM 8
#define TN 8

typedef _Float16 half8_t __attribute__((ext_vector_type(8)));
typedef float f32x4_t __attribute__((ext_vector_type(4)));

// Monotone encoding: unsigned compare order == float compare order.
__device__ __forceinline__ unsigned int mono_enc(float f) {
    unsigned int u = __float_as_uint(f);
    return (u & 0x80000000u) ? ~u : (u | 0x80000000u);
}
__device__ __forceinline__ float mono_dec(unsigned int e) {
    return __uint_as_float((e & 0x80000000u) ? (e ^ 0x80000000u) : ~e);
}

// ======================= legacy (fallback) path =======================

__global__ __launch_bounds__(256) void norms_kernel(const float* __restrict__ Q,
                                                    const float* __restrict__ P,
                                                    float* __restrict__ invq,
                                                    float* __restrict__ invp) {
    int n = blockIdx.x * blockDim.x + threadIdx.x;
    if (n >= N_PIX) return;
    float sq = 0.f, sp = 0.f;
    for (int c = 0; c < CCH; ++c) {
        float a = Q[(size_t)c * N_PIX + n];
        float b = P[(size_t)c * N_PIX + n];
        sq = fmaf(a, a, sq);
        sp = fmaf(b, b, sp);
    }
    invq[n] = 1.0f / sqrtf(sq);
    invp[n] = 1.0f / sqrtf(sp);
}

__device__ __forceinline__ int local_row(int ty, int i) {
    return (i < 4) ? (ty * 4 + i) : (64 + ty * 4 + (i - 4));
}
__device__ __forceinline__ int local_col(int tx, int j) {
    return (j < 4) ? (tx * 4 + j) : (64 + tx * 4 + (j - 4));
}

__global__ __launch_bounds__(256) void gemm_kernel(const float* __restrict__ Q,
                                                   const float* __restrict__ P,
                                                   const float* __restrict__ invq,
                                                   const float* __restrict__ invp,
                                                   float* __restrict__ sim,
                                                   unsigned long long* __restrict__ row_best,
                                                   unsigned long long* __restrict__ col_best) {
    __shared__ union SH {
        struct { float A[BK][BM]; float B[BK][BN]; } t;
        unsigned long long red[16][128];
    } sh;

    const int tid = threadIdx.x;
    const int tx = tid & 15;
    const int ty = tid >> 4;
    const int n0 = blockIdx.y * BM;
    const int m0 = blockIdx.x * BN;

    float acc[TM][TN];
#pragma unroll
    for (int i = 0; i < TM; ++i)
#pragma unroll
        for (int j = 0; j < TN; ++j) acc[i][j] = 0.f;

    for (int kk = 0; kk < CCH; kk += BK) {
#pragma unroll
        for (int rep = 0; rep < 2; ++rep) {
            int idx = tid + rep * 256;
            int row = idx >> 5;
            int c4  = idx & 31;
            float4 av = *(const float4*)&Q[(size_t)(kk + row) * N_PIX + n0 + c4 * 4];
            float4 bv = *(const float4*)&P[(size_t)(kk + row) * N_PIX + m0 + c4 * 4];
            *(float4*)&sh.t.A[row][c4 * 4] = av;
            *(float4*)&sh.t.B[row][c4 * 4] = bv;
        }
        __syncthreads();
#pragma unroll
        for (int k = 0; k < BK; ++k) {
            float a[TM], b[TN];
            *(float4*)&a[0] = *(const float4*)&sh.t.A[k][ty * 4];
            *(float4*)&a[4] = *(const float4*)&sh.t.A[k][ty * 4 + 64];
            *(float4*)&b[0] = *(const float4*)&sh.t.B[k][tx * 4];
            *(float4*)&b[4] = *(const float4*)&sh.t.B[k][tx * 4 + 64];
#pragma unroll
            for (int i = 0; i < TM; ++i)
#pragma unroll
                for (int j = 0; j < TN; ++j)
                    acc[i][j] = fmaf(a[i], b[j], acc[i][j]);
        }
        __syncthreads();
    }

    float iq[TM], ip[TN];
#pragma unroll
    for (int i = 0; i < TM; ++i) iq[i] = invq[n0 + local_row(ty, i)];
#pragma unroll
    for (int j = 0; j < TN; ++j) ip[j] = invp[m0 + local_col(tx, j)];
#pragma unroll
    for (int i = 0; i < TM; ++i)
#pragma unroll
        for (int j = 0; j < TN; ++j) acc[i][j] *= iq[i] * ip[j];

#pragma unroll
    for (int i = 0; i < TM; ++i) {
        int n = n0 + local_row(ty, i);
        float4 v0 = make_float4(acc[i][0], acc[i][1], acc[i][2], acc[i][3]);
        float4 v1 = make_float4(acc[i][4], acc[i][5], acc[i][6], acc[i][7]);
        float* dst = &sim[(size_t)n * N_PIX + m0];
        *(float4*)(dst + tx * 4) = v0;
        *(float4*)(dst + 64 + tx * 4) = v1;
    }

#pragma unroll
    for (int i = 0; i < TM; ++i) {
        float best = acc[i][0]; int bj = 0;
#pragma unroll
        for (int j = 1; j < TN; ++j)
            if (acc[i][j] > best) { best = acc[i][j]; bj = j; }
        unsigned int gcol = (unsigned int)(m0 + local_col(tx, bj));
        sh.red[tx][local_row(ty, i)] =
            ((unsigned long long)mono_enc(best) << 32) | (unsigned long long)(0xFFFFFFFFu - gcol);
    }
    __syncthreads();
    if (tid < 128) {
        unsigned long long best = sh.red[0][tid];
#pragma unroll
        for (int x = 1; x < 16; ++x) {
            unsigned long long v = sh.red[x][tid];
            if (v > best) best = v;
        }
        atomicMax(&row_best[n0 + tid], best);
    }
    __syncthreads();

#pragma unroll
    for (int j = 0; j < TN; ++j) {
        float best = acc[0][j]; int bi = 0;
#pragma unroll
        for (int i = 1; i < TM; ++i)
            if (acc[i][j] > best) { best = acc[i][j]; bi = i; }
        unsigned int grow = (unsigned int)(n0 + local_row(ty, bi));
        sh.red[ty][local_col(tx, j)] =
            ((unsigned long long)mono_enc(best) << 32) | (unsigned long long)(0xFFFFFFFFu - grow);
    }
    __syncthreads();
    if (tid < 128) {
        unsigned long long best = sh.red[0][tid];
#pragma unroll
        for (int x = 1; x < 16; ++x) {
            unsigned long long v = sh.red[x][tid];
            if (v > best) best = v;
        }
        atomicMax(&col_best[m0 + tid], best);
    }
}

// ======================= fast (MFMA) path =======================

// Norms with 4-way k-banding: 144 blocks x 256 threads, 64 pixels/block.
__global__ __launch_bounds__(256) void norms4_kernel(const float* __restrict__ Q,
                                                     const float* __restrict__ P,
                                                     float* __restrict__ invq,
                                                     float* __restrict__ invp) {
    __shared__ float rq[4][64];
    __shared__ float rp[4][64];
    const int lane = threadIdx.x & 63;
    const int band = threadIdx.x >> 6;
    const int n = blockIdx.x * 64 + lane;
    float sq = 0.f, sp = 0.f;
    for (int k = band * 64; k < (band + 1) * 64; ++k) {
        float a = Q[(size_t)k * N_PIX + n];
        float b = P[(size_t)k * N_PIX + n];
        sq = fmaf(a, a, sq);
        sp = fmaf(b, b, sp);
    }
    rq[band][lane] = sq;
    rp[band][lane] = sp;
    __syncthreads();
    if (threadIdx.x < 64) {
        float tq = rq[0][lane] + rq[1][lane] + rq[2][lane] + rq[3][lane];
        float tp = rp[0][lane] + rp[1][lane] + rp[2][lane] + rp[3][lane];
        invq[n] = 1.0f / sqrtf(tq);
        invp[n] = 1.0f / sqrtf(tp);
    }
}

// Split fp32 -> (hi, lo) fp16, stored as [C/2][N] dwords packing k-pairs
// (k even in low half, k odd in high half) == exact MFMA fragment register
// layout, so the GEMM needs zero unpack instructions.
__global__ __launch_bounds__(256) void split_kernel(const float* __restrict__ Q,
                                                    const float* __restrict__ P,
                                                    unsigned int* __restrict__ qh,
                                                    unsigned int* __restrict__ ql,
                                                    unsigned int* __restrict__ ph,
                                                    unsigned int* __restrict__ pl) {
    const int n = blockIdx.x * 256 + threadIdx.x;
    const int k2 = blockIdx.y;
    const size_t i0 = (size_t)(2 * k2) * N_PIX + n;
    const size_t o  = (size_t)k2 * N_PIX + n;

    float a0 = Q[i0], a1 = Q[i0 + N_PIX];
    unsigned short qh0 = __half_as_ushort(__float2half(a0));
    unsigned short qh1 = __half_as_ushort(__float2half(a1));
    float qr0 = a0 - __half2float(__ushort_as_half(qh0));
    float qr1 = a1 - __half2float(__ushort_as_half(qh1));
    unsigned short ql0 = __half_as_ushort(__float2half(qr0));
    unsigned short ql1 = __half_as_ushort(__float2half(qr1));
    qh[o] = (unsigned int)qh0 | ((unsigned int)qh1 << 16);
    ql[o] = (unsigned int)ql0 | ((unsigned int)ql1 << 16);

    float b0 = P[i0], b1 = P[i0 + N_PIX];
    unsigned short ph0 = __half_as_ushort(__float2half(b0));
    unsigned short ph1 = __half_as_ushort(__float2half(b1));
    float pr0 = b0 - __half2float(__ushort_as_half(ph0));
    float pr1 = b1 - __half2float(__ushort_as_half(ph1));
    unsigned short pl0 = __half_as_ushort(__float2half(pr0));
    unsigned short pl1 = __half_as_ushort(__float2half(pr1));
    ph[o] = (unsigned int)ph0 | ((unsigned int)ph1 << 16);
    pl[o] = (unsigned int)pl0 | ((unsigned int)pl1 << 16);
}

// 128x128 tile, 4 waves, wave = 64x64 = 4x4 fragments of 16x16x32 f16 MFMA.
// sim = Qn^T Pn via 2-term fp16 split: hi*hi + hi*lo + lo*hi (lo*lo ~ 2^-22, dropped).
// No LDS, no barriers in the K-loop; fragments loaded directly from the packed
// dword arrays (per-inst: 4 x 64B coalesced segments).
__global__ __launch_bounds__(256, 2) void mfma_gemm_kernel(
        const unsigned int* __restrict__ QH, const unsigned int* __restrict__ QL,
        const unsigned int* __restrict__ PH, const unsigned int* __restrict__ PL,
        const float* __restrict__ invq, const float* __restrict__ invp,
        float* __restrict__ sim,
        unsigned long long* __restrict__ row_best,
        unsigned long long* __restrict__ col_best) {
    // XCD-bijective swizzle: 5184 blocks = 8 XCDs x 648; each XCD sweeps 9
    // full row-panels so its Q-panel (131 KB) stays L2-resident.
    const unsigned int bid = blockIdx.x;
    const unsigned int nb = (bid & 7u) * 648u + (bid >> 3);
    const unsigned int by = nb / 72u;
    const unsigned int bx = nb % 72u;

    const int tid = threadIdx.x;
    const int l  = tid & 63;
    const int w  = tid >> 6;
    const int rl = l & 15;   // A-row / B-col / D-col within fragment
    const int kg = l >> 4;   // k-group (0..3); also D-row group
    const int r0 = (int)by * 128 + (w >> 1) * 64;  // query rows
    const int c0 = (int)bx * 128 + (w & 1) * 64;   // projection cols

    const f32x4_t zero4 = {0.f, 0.f, 0.f, 0.f};
    f32x4_t acc[4][4];
#pragma unroll
    for (int i = 0; i < 4; ++i)
#pragma unroll
        for (int j = 0; j < 4; ++j) acc[i][j] = zero4;

    const unsigned int rA = (unsigned int)(r0 + rl);
    const unsigned int cB = (unsigned int)(c0 + rl);

    union Frag { unsigned int u[4]; half8_t h; };

    for (int kd0 = 0; kd0 < 128; kd0 += 16) {  // 16 dword-rows = K 32 per step
        const int kd = kd0 + kg * 4;
        Frag ah[4], al[4], bh[4], bl[4];
#pragma unroll
        for (int j = 0; j < 4; ++j) {
            const unsigned int* qhp = QH + (size_t)(kd + j) * N_PIX + rA;
            const unsigned int* qlp = QL + (size_t)(kd + j) * N_PIX + rA;
            const unsigned int* php = PH + (size_t)(kd + j) * N_PIX + cB;
            const unsigned int* plp = PL + (size_t)(kd + j) * N_PIX + cB;
#pragma unroll
            for (int f = 0; f < 4; ++f) {
                ah[f].u[j] = qhp[f * 16];
                al[f].u[j] = qlp[f * 16];
                bh[f].u[j] = php[f * 16];
                bl[f].u[j] = plp[f * 16];
            }
        }
#pragma unroll
        for (int fr = 0; fr < 4; ++fr)
#pragma unroll
            for (int fc = 0; fc < 4; ++fc) {
                acc[fr][fc] = __builtin_amdgcn_mfma_f32_16x16x32_f16(ah[fr].h, bh[fc].h, acc[fr][fc], 0, 0, 0);
                acc[fr][fc] = __builtin_amdgcn_mfma_f32_16x16x32_f16(ah[fr].h, bl[fc].h, acc[fr][fc], 0, 0, 0);
                acc[fr][fc] = __builtin_amdgcn_mfma_f32_16x16x32_f16(al[fr].h, bh[fc].h, acc[fr][fc], 0, 0, 0);
            }
    }

    // ---- scale by inverse norms; store sim (nontemporal: 340 MB stream) ----
    float iq[4][4];
#pragma unroll
    for (int fr = 0; fr < 4; ++fr) {
        const float4 v = *(const float4*)&invq[r0 + fr * 16 + kg * 4];
        iq[fr][0] = v.x; iq[fr][1] = v.y; iq[fr][2] = v.z; iq[fr][3] = v.w;
    }
    float ip[4];
#pragma unroll
    for (int fc = 0; fc < 4; ++fc) ip[fc] = invp[c0 + fc * 16 + rl];

#pragma unroll
    for (int fr = 0; fr < 4; ++fr)
#pragma unroll
        for (int j = 0; j < 4; ++j) {
            const int r = r0 + fr * 16 + kg * 4 + j;
            float* dst = sim + (size_t)r * N_PIX;
#pragma unroll
            for (int fc = 0; fc < 4; ++fc) {
                float v = acc[fr][fc][j] * iq[fr][j] * ip[fc];
                acc[fr][fc][j] = v;
                __builtin_nontemporal_store(v, dst + c0 + fc * 16 + rl);
            }
        }

    // ---- row bests: reduce over this wave's 64 cols (fc in-lane, rl x-lane) ----
#pragma unroll
    for (int fr = 0; fr < 4; ++fr)
#pragma unroll
        for (int j = 0; j < 4; ++j) {
            float best = acc[fr][0][j];
            int bf = 0;
#pragma unroll
            for (int fc = 1; fc < 4; ++fc)
                if (acc[fr][fc][j] > best) { best = acc[fr][fc][j]; bf = fc; }
            const unsigned int gcol = (unsigned int)(c0 + bf * 16 + rl);
            unsigned long long key = ((unsigned long long)mono_enc(best) << 32)
                                   | (unsigned long long)(0xFFFFFFFFu - gcol);
#pragma unroll
            for (int m = 1; m < 16; m <<= 1) {
                unsigned long long o = __shfl_xor(key, m, 64);
                if (o > key) key = o;
            }
            if (rl == 0)
                atomicMax(&row_best[r0 + fr * 16 + kg * 4 + j], key);
        }

    // ---- col bests: reduce over this wave's 64 rows (fr,j in-lane, kg x-lane) ----
#pragma unroll
    for (int fc = 0; fc < 4; ++fc) {
        float best = acc[0][fc][0];
        unsigned int brow = (unsigned int)(r0 + kg * 4);
#pragma unroll
        for (int fr = 0; fr < 4; ++fr)
#pragma unroll
            for (int j = 0; j < 4; ++j) {
                float v = acc[fr][fc][j];  // rows scanned in increasing order
                unsigned int rr = (unsigned int)(r0 + fr * 16 + kg * 4 + j);
                if (v > best) { best = v; brow = rr; }
            }
        unsigned long long key = ((unsigned long long)mono_enc(best) << 32)
                               | (unsigned long long)(0xFFFFFFFFu - brow);
#pragma unroll
        for (int m = 16; m < 64; m <<= 1) {
            unsigned long long o = __shfl_xor(key, m, 64);
            if (o > key) key = o;
        }
        if (kg == 0)
            atomicMax(&col_best[c0 + fc * 16 + rl], key);
    }
}

// ======================= shared epilogue =======================

__global__ __launch_bounds__(256) void epilogue_kernel(const unsigned long long* __restrict__ row_best,
                                                       const unsigned long long* __restrict__ col_best,
                                                       float* __restrict__ out) {
    int j = blockIdx.x * blockDim.x + threadIdx.x;
    if (j >= N_PIX) return;
    unsigned long long cb = col_best[j];
    unsigned int q_idx = 0xFFFFFFFFu - (unsigned int)(cb & 0xFFFFFFFFull);
    float simval = mono_dec((unsigned int)(cb >> 32));
    unsigned long long rb = row_best[q_idx];
    unsigned int rm = 0xFFFFFFFFu - (unsigned int)(rb & 0xFFFFFFFFull);
    bool mutual = (rm == (unsigned int)j) && (simval > 0.9f);
    int qd = (int)(q_idx / W_), qm = (int)(q_idx % W_);
    int pd = j / W_, pm = j % W_;
    bool valid = mutual && (qd + 1 < H_) && (pd + 1 < H_);
    size_t base = (size_t)N_PIX * N_PIX;
    out[base + 0 * (size_t)N_PIX + j] = valid ? 1.0f : 0.0f;
    out[base + 1 * (size_t)N_PIX + j] = (float)q_idx;
    out[base + 2 * (size_t)N_PIX + j] = (float)qd;
    out[base + 3 * (size_t)N_PIX + j] = (float)qm;
    out[base + 4 * (size_t)N_PIX + j] = (float)pd;
    out[base + 5 * (size_t)N_PIX + j] = (float)pm;
}

extern "C" void kernel_launch(void* const* d_in, const int* in_sizes, int n_in,
                              void* d_out, int out_size, void* d_ws, size_t ws_size,
                              hipStream_t stream) {
    const float* Q = (const float*)d_in[0];
    const float* P = (const float*)d_in[1];
    float* out = (float*)d_out;

    unsigned long long* row_best = (unsigned long long*)d_ws;
    unsigned long long* col_best = row_best + N_PIX;
    float* invq = (float*)(col_best + N_PIX);
    float* invp = invq + N_PIX;

    hipMemsetAsync(d_ws, 0, 2 * N_PIX * sizeof(unsigned long long), stream);

    const size_t base_bytes = 2 * N_PIX * sizeof(unsigned long long) + 2 * N_PIX * sizeof(float);
    const size_t arr_dwords = (size_t)(CCH / 2) * N_PIX;
    const size_t need = base_bytes + 4 * arr_dwords * sizeof(unsigned int);

    if (ws_size >= need) {
        unsigned int* qh = (unsigned int*)((char*)d_ws + base_bytes);
        unsigned int* ql = qh + arr_dwords;
        unsigned int* ph = ql + arr_dwords;
        unsigned int* pl = ph + arr_dwords;

        norms4_kernel<<<N_PIX / 64, 256, 0, stream>>>(Q, P, invq, invp);
        split_kernel<<<dim3(N_PIX / 256, CCH / 2), 256, 0, stream>>>(Q, P, qh, ql, ph, pl);
        mfma_gemm_kernel<<<5184, 256, 0, stream>>>(qh, ql, ph, pl, invq, invp,
                                                   out, row_best, col_best);
    } else {
        // workspace too small for split arrays: proven legacy path
        norms_kernel<<<N_PIX / 256, 256, 0, stream>>>(Q, P, invq, invp);
        dim3 grid(N_PIX / BN, N_PIX / BM);
        gemm_kernel<<<grid, 256, 0, stream>>>(Q, P, invq, invp, out, row_best, col_best);
    }

    epilogue_kernel<<<N_PIX / 256, 256, 0, stream>>>(row_best, col_best, out);
}

// Round 2
// 485.212 us; speedup vs baseline: 1.9637x; 1.1153x over previous
//
#include <hip/hip_runtime.h>
#include <hip/hip_fp16.h>

#define N_PIX 9216
#define CCH 256
#define W_ 96
#define H_ 96
#define BM 128
#define BN 128
#define BK 16
#define TM 8
#define TN 8

typedef _Float16 half8_t __attribute__((ext_vector_type(8)));
typedef float f32x4_t __attribute__((ext_vector_type(4)));

// Monotone encoding: unsigned compare order == float compare order.
__device__ __forceinline__ unsigned int mono_enc(float f) {
    unsigned int u = __float_as_uint(f);
    return (u & 0x80000000u) ? ~u : (u | 0x80000000u);
}
__device__ __forceinline__ float mono_dec(unsigned int e) {
    return __uint_as_float((e & 0x80000000u) ? (e ^ 0x80000000u) : ~e);
}

// ======================= legacy (fallback) path =======================

__global__ __launch_bounds__(256) void norms_kernel(const float* __restrict__ Q,
                                                    const float* __restrict__ P,
                                                    float* __restrict__ invq,
                                                    float* __restrict__ invp) {
    int n = blockIdx.x * blockDim.x + threadIdx.x;
    if (n >= N_PIX) return;
    float sq = 0.f, sp = 0.f;
    for (int c = 0; c < CCH; ++c) {
        float a = Q[(size_t)c * N_PIX + n];
        float b = P[(size_t)c * N_PIX + n];
        sq = fmaf(a, a, sq);
        sp = fmaf(b, b, sp);
    }
    invq[n] = 1.0f / sqrtf(sq);
    invp[n] = 1.0f / sqrtf(sp);
}

__device__ __forceinline__ int local_row(int ty, int i) {
    return (i < 4) ? (ty * 4 + i) : (64 + ty * 4 + (i - 4));
}
__device__ __forceinline__ int local_col(int tx, int j) {
    return (j < 4) ? (tx * 4 + j) : (64 + tx * 4 + (j - 4));
}

__global__ __launch_bounds__(256) void gemm_kernel(const float* __restrict__ Q,
                                                   const float* __restrict__ P,
                                                   const float* __restrict__ invq,
                                                   const float* __restrict__ invp,
                                                   float* __restrict__ sim,
                                                   unsigned long long* __restrict__ row_best,
                                                   unsigned long long* __restrict__ col_best) {
    __shared__ union SH {
        struct { float A[BK][BM]; float B[BK][BN]; } t;
        unsigned long long red[16][128];
    } sh;

    const int tid = threadIdx.x;
    const int tx = tid & 15;
    const int ty = tid >> 4;
    const int n0 = blockIdx.y * BM;
    const int m0 = blockIdx.x * BN;

    float acc[TM][TN];
#pragma unroll
    for (int i = 0; i < TM; ++i)
#pragma unroll
        for (int j = 0; j < TN; ++j) acc[i][j] = 0.f;

    for (int kk = 0; kk < CCH; kk += BK) {
#pragma unroll
        for (int rep = 0; rep < 2; ++rep) {
            int idx = tid + rep * 256;
            int row = idx >> 5;
            int c4  = idx & 31;
            float4 av = *(const float4*)&Q[(size_t)(kk + row) * N_PIX + n0 + c4 * 4];
            float4 bv = *(const float4*)&P[(size_t)(kk + row) * N_PIX + m0 + c4 * 4];
            *(float4*)&sh.t.A[row][c4 * 4] = av;
            *(float4*)&sh.t.B[row][c4 * 4] = bv;
        }
        __syncthreads();
#pragma unroll
        for (int k = 0; k < BK; ++k) {
            float a[TM], b[TN];
            *(float4*)&a[0] = *(const float4*)&sh.t.A[k][ty * 4];
            *(float4*)&a[4] = *(const float4*)&sh.t.A[k][ty * 4 + 64];
            *(float4*)&b[0] = *(const float4*)&sh.t.B[k][tx * 4];
            *(float4*)&b[4] = *(const float4*)&sh.t.B[k][tx * 4 + 64];
#pragma unroll
            for (int i = 0; i < TM; ++i)
#pragma unroll
                for (int j = 0; j < TN; ++j)
                    acc[i][j] = fmaf(a[i], b[j], acc[i][j]);
        }
        __syncthreads();
    }

    float iq[TM], ip[TN];
#pragma unroll
    for (int i = 0; i < TM; ++i) iq[i] = invq[n0 + local_row(ty, i)];
#pragma unroll
    for (int j = 0; j < TN; ++j) ip[j] = invp[m0 + local_col(tx, j)];
#pragma unroll
    for (int i = 0; i < TM; ++i)
#pragma unroll
        for (int j = 0; j < TN; ++j) acc[i][j] *= iq[i] * ip[j];

#pragma unroll
    for (int i = 0; i < TM; ++i) {
        int n = n0 + local_row(ty, i);
        float4 v0 = make_float4(acc[i][0], acc[i][1], acc[i][2], acc[i][3]);
        float4 v1 = make_float4(acc[i][4], acc[i][5], acc[i][6], acc[i][7]);
        float* dst = &sim[(size_t)n * N_PIX + m0];
        *(float4*)(dst + tx * 4) = v0;
        *(float4*)(dst + 64 + tx * 4) = v1;
    }

#pragma unroll
    for (int i = 0; i < TM; ++i) {
        float best = acc[i][0]; int bj = 0;
#pragma unroll
        for (int j = 1; j < TN; ++j)
            if (acc[i][j] > best) { best = acc[i][j]; bj = j; }
        unsigned int gcol = (unsigned int)(m0 + local_col(tx, bj));
        sh.red[tx][local_row(ty, i)] =
            ((unsigned long long)mono_enc(best) << 32) | (unsigned long long)(0xFFFFFFFFu - gcol);
    }
    __syncthreads();
    if (tid < 128) {
        unsigned long long best = sh.red[0][tid];
#pragma unroll
        for (int x = 1; x < 16; ++x) {
            unsigned long long v = sh.red[x][tid];
            if (v > best) best = v;
        }
        atomicMax(&row_best[n0 + tid], best);
    }
    __syncthreads();

#pragma unroll
    for (int j = 0; j < TN; ++j) {
        float best = acc[0][j]; int bi = 0;
#pragma unroll
        for (int i = 1; i < TM; ++i)
            if (acc[i][j] > best) { best = acc[i][j]; bi = i; }
        unsigned int grow = (unsigned int)(n0 + local_row(ty, bi));
        sh.red[ty][local_col(tx, j)] =
            ((unsigned long long)mono_enc(best) << 32) | (unsigned long long)(0xFFFFFFFFu - grow);
    }
    __syncthreads();
    if (tid < 128) {
        unsigned long long best = sh.red[0][tid];
#pragma unroll
        for (int x = 1; x < 16; ++x) {
            unsigned long long v = sh.red[x][tid];
            if (v > best) best = v;
        }
        atomicMax(&col_best[m0 + tid], best);
    }
}

// ======================= fast (MFMA) path =======================

__device__ __forceinline__ unsigned int pack_pair(float x, float y, float& rx, float& ry) {
    __half hx = __float2half(x), hy = __float2half(y);
    rx = x - __half2float(hx);
    ry = y - __half2float(hy);
    return (unsigned int)__half_as_ushort(hx) | ((unsigned int)__half_as_ushort(hy) << 16);
}

// Fused norms + fp16-split kernel. Output layout is FRAGMENT-MAJOR:
// for kb = dword-row/4 (0..31), array[kb*N_PIX + n] is a uint4 holding the
// 4 k-pair dwords (k = kb*8 .. kb*8+7) of pixel n == exactly one MFMA
// fragment register group, loadable with a single global_load_dwordx4.
__global__ __launch_bounds__(256) void prep_kernel(const float* __restrict__ Q,
                                                   const float* __restrict__ P,
                                                   uint4* __restrict__ qh,
                                                   uint4* __restrict__ ql,
                                                   uint4* __restrict__ ph,
                                                   uint4* __restrict__ pl,
                                                   float* __restrict__ invq,
                                                   float* __restrict__ invp) {
    __shared__ float rq[4][64];
    __shared__ float rp[4][64];
    const int lane = threadIdx.x & 63;
    const int band = threadIdx.x >> 6;
    const int n = blockIdx.x * 64 + lane;
    float sq = 0.f, sp = 0.f;
    for (int kb = band * 8; kb < band * 8 + 8; ++kb) {
        float a[8], b[8];
#pragma unroll
        for (int t = 0; t < 8; ++t) {
            a[t] = Q[(size_t)(kb * 8 + t) * N_PIX + n];
            b[t] = P[(size_t)(kb * 8 + t) * N_PIX + n];
        }
#pragma unroll
        for (int t = 0; t < 8; ++t) {
            sq = fmaf(a[t], a[t], sq);
            sp = fmaf(b[t], b[t], sp);
        }
        uint4 vqh, vql, vph, vpl;
        unsigned int* uqh = (unsigned int*)&vqh;
        unsigned int* uql = (unsigned int*)&vql;
        unsigned int* uph = (unsigned int*)&vph;
        unsigned int* upl = (unsigned int*)&vpl;
#pragma unroll
        for (int j = 0; j < 4; ++j) {
            float r0, r1;
            uqh[j] = pack_pair(a[2 * j], a[2 * j + 1], r0, r1);
            uql[j] = (unsigned int)__half_as_ushort(__float2half(r0))
                   | ((unsigned int)__half_as_ushort(__float2half(r1)) << 16);
            uph[j] = pack_pair(b[2 * j], b[2 * j + 1], r0, r1);
            upl[j] = (unsigned int)__half_as_ushort(__float2half(r0))
                   | ((unsigned int)__half_as_ushort(__float2half(r1)) << 16);
        }
        size_t o = (size_t)kb * N_PIX + n;
        qh[o] = vqh; ql[o] = vql; ph[o] = vph; pl[o] = vpl;
    }
    rq[band][lane] = sq;
    rp[band][lane] = sp;
    __syncthreads();
    if (threadIdx.x < 64) {
        float tq = rq[0][lane] + rq[1][lane] + rq[2][lane] + rq[3][lane];
        float tp = rp[0][lane] + rp[1][lane] + rp[2][lane] + rp[3][lane];
        invq[n] = 1.0f / sqrtf(tq);
        invp[n] = 1.0f / sqrtf(tp);
    }
}

// 128x128 tile, 4 waves, wave = 64x64 = 4x4 fragments of 16x16x32 f16 MFMA.
// sim = Qn^T Pn via 2-term fp16 split: hi*hi + hi*lo + lo*hi.
// Fragment-major operands: one dwordx4 load per fragment (16 VMEM/K-step).
// Sim stores go through a per-wave LDS transpose so every store instruction
// writes 256 B contiguous per row (full L2 lines -> no read-for-ownership).
__global__ __launch_bounds__(256, 3) void mfma_gemm_kernel(
        const uint4* __restrict__ QH, const uint4* __restrict__ QL,
        const uint4* __restrict__ PH, const uint4* __restrict__ PL,
        const float* __restrict__ invq, const float* __restrict__ invp,
        float* __restrict__ sim,
        unsigned long long* __restrict__ row_best,
        unsigned long long* __restrict__ col_best) {
    // Serpentine XCD swizzle: each XCD owns 9 by-panels; within it, walk
    // 8-wide bx-groups so the ~96 resident blocks/XCD touch ~2.2 MB (L2-fits).
    const unsigned int bid = blockIdx.x;
    const unsigned int xcd = bid & 7u;
    const unsigned int nbl = bid >> 3;           // 0..647
    const unsigned int gg  = nbl / 72u;          // 0..8  bx-group
    const unsigned int rr  = nbl % 72u;
    const unsigned int by  = xcd * 9u + (rr >> 3);   // 0..71
    const unsigned int bx  = gg * 8u + (rr & 7u);    // 0..71

    const int tid = threadIdx.x;
    const int l  = tid & 63;
    const int w  = tid >> 6;
    const int rl = l & 15;   // fragment row (A) / col (B,D)
    const int kg = l >> 4;   // k-group; also D-row group
    const int r0 = (int)by * 128 + (w >> 1) * 64;  // query rows
    const int c0 = (int)bx * 128 + (w & 1) * 64;   // projection cols

    // per-wave store-transpose buffer: 16 rows x 64 cols, stride 68 (bank-spread)
    __shared__ float st[4][16][68];

    const f32x4_t zero4 = {0.f, 0.f, 0.f, 0.f};
    f32x4_t acc[4][4];
#pragma unroll
    for (int i = 0; i < 4; ++i)
#pragma unroll
        for (int j = 0; j < 4; ++j) acc[i][j] = zero4;

    const int rA = r0 + rl;
    const int cB = c0 + rl;

    const uint4* pqh = QH + (size_t)kg * N_PIX + rA;
    const uint4* pql = QL + (size_t)kg * N_PIX + rA;
    const uint4* pph = PH + (size_t)kg * N_PIX + cB;
    const uint4* ppl = PL + (size_t)kg * N_PIX + cB;

#pragma unroll 2
    for (int ks = 0; ks < 8; ++ks) {
        half8_t ah[4], al4[4], bh4[4], bl4[4];
#pragma unroll
        for (int f = 0; f < 4; ++f) {
            ah[f]  = *(const half8_t*)(pqh + f * 16);
            al4[f] = *(const half8_t*)(pql + f * 16);
            bh4[f] = *(const half8_t*)(pph + f * 16);
            bl4[f] = *(const half8_t*)(ppl + f * 16);
        }
        pqh += 4 * N_PIX; pql += 4 * N_PIX; pph += 4 * N_PIX; ppl += 4 * N_PIX;
#pragma unroll
        for (int fr = 0; fr < 4; ++fr)
#pragma unroll
            for (int fc = 0; fc < 4; ++fc) {
                acc[fr][fc] = __builtin_amdgcn_mfma_f32_16x16x32_f16(ah[fr],  bh4[fc], acc[fr][fc], 0, 0, 0);
                acc[fr][fc] = __builtin_amdgcn_mfma_f32_16x16x32_f16(ah[fr],  bl4[fc], acc[fr][fc], 0, 0, 0);
                acc[fr][fc] = __builtin_amdgcn_mfma_f32_16x16x32_f16(al4[fr], bh4[fc], acc[fr][fc], 0, 0, 0);
            }
    }

    // ---- scale by inverse norms (in-register) ----
    float iq[4][4];
#pragma unroll
    for (int fr = 0; fr < 4; ++fr) {
        const float4 v = *(const float4*)&invq[r0 + fr * 16 + kg * 4];
        iq[fr][0] = v.x; iq[fr][1] = v.y; iq[fr][2] = v.z; iq[fr][3] = v.w;
    }
    float ip[4];
#pragma unroll
    for (int fc = 0; fc < 4; ++fc) ip[fc] = invp[c0 + fc * 16 + rl];

#pragma unroll
    for (int fr = 0; fr < 4; ++fr)
#pragma unroll
        for (int fc = 0; fc < 4; ++fc)
#pragma unroll
            for (int j = 0; j < 4; ++j)
                acc[fr][fc][j] *= iq[fr][j] * ip[fc];

    // ---- row bests: reduce over this wave's 64 cols (fc in-lane, rl x-lane) ----
#pragma unroll
    for (int fr = 0; fr < 4; ++fr)
#pragma unroll
        for (int j = 0; j < 4; ++j) {
            float best = acc[fr][0][j];
            int bf = 0;
#pragma unroll
            for (int fc = 1; fc < 4; ++fc)
                if (acc[fr][fc][j] > best) { best = acc[fr][fc][j]; bf = fc; }
            const unsigned int gcol = (unsigned int)(c0 + bf * 16 + rl);
            unsigned long long key = ((unsigned long long)mono_enc(best) << 32)
                                   | (unsigned long long)(0xFFFFFFFFu - gcol);
#pragma unroll
            for (int m = 1; m < 16; m <<= 1) {
                unsigned long long o = __shfl_xor(key, m, 64);
                if (o > key) key = o;
            }
            if (rl == 0)
                atomicMax(&row_best[r0 + fr * 16 + kg * 4 + j], key);
        }

    // ---- col bests: reduce over this wave's 64 rows (fr,j in-lane, kg x-lane) ----
#pragma unroll
    for (int fc = 0; fc < 4; ++fc) {
        float best = acc[0][fc][0];
        unsigned int brow = (unsigned int)(r0 + kg * 4);
#pragma unroll
        for (int fr = 0; fr < 4; ++fr)
#pragma unroll
            for (int j = 0; j < 4; ++j) {
                float v = acc[fr][fc][j];  // rows scanned in increasing order
                unsigned int rr2 = (unsigned int)(r0 + fr * 16 + kg * 4 + j);
                if (v > best) { best = v; brow = rr2; }
            }
        unsigned long long key = ((unsigned long long)mono_enc(best) << 32)
                               | (unsigned long long)(0xFFFFFFFFu - brow);
#pragma unroll
        for (int m = 16; m < 64; m <<= 1) {
            unsigned long long o = __shfl_xor(key, m, 64);
            if (o > key) key = o;
        }
        if (kg == 0)
            atomicMax(&col_best[c0 + fc * 16 + rl], key);
    }

    // ---- sim stores via per-wave LDS transpose: full-line writes ----
#pragma unroll
    for (int fr = 0; fr < 4; ++fr) {
        asm volatile("s_waitcnt lgkmcnt(0)" ::: "memory");  // prior fr's reads done
#pragma unroll
        for (int fc = 0; fc < 4; ++fc)
#pragma unroll
            for (int j = 0; j < 4; ++j)
                st[w][kg * 4 + j][fc * 16 + rl] = acc[fr][fc][j];
        asm volatile("s_waitcnt lgkmcnt(0)" ::: "memory");  // writes visible to wave
#pragma unroll
        for (int pass = 0; pass < 4; ++pass) {
            const int rowL = pass * 4 + kg;
            const f32x4_t v = *(const f32x4_t*)&st[w][rowL][rl * 4];
            const int gr = r0 + fr * 16 + rowL;
            // 16 lanes (rl) x 16 B contiguous per row = 256 B runs, 4 rows/inst
            __builtin_nontemporal_store(v, (f32x4_t*)(sim + (size_t)gr * N_PIX + c0 + rl * 4));
        }
    }
}

// ======================= shared epilogue =======================

__global__ __launch_bounds__(256) void epilogue_kernel(const unsigned long long* __restrict__ row_best,
                                                       const unsigned long long* __restrict__ col_best,
                                                       float* __restrict__ out) {
    int j = blockIdx.x * blockDim.x + threadIdx.x;
    if (j >= N_PIX) return;
    unsigned long long cb = col_best[j];
    unsigned int q_idx = 0xFFFFFFFFu - (unsigned int)(cb & 0xFFFFFFFFull);
    float simval = mono_dec((unsigned int)(cb >> 32));
    unsigned long long rb = row_best[q_idx];
    unsigned int rm = 0xFFFFFFFFu - (unsigned int)(rb & 0xFFFFFFFFull);
    bool mutual = (rm == (unsigned int)j) && (simval > 0.9f);
    int qd = (int)(q_idx / W_), qm = (int)(q_idx % W_);
    int pd = j / W_, pm = j % W_;
    bool valid = mutual && (qd + 1 < H_) && (pd + 1 < H_);
    size_t base = (size_t)N_PIX * N_PIX;
    out[base + 0 * (size_t)N_PIX + j] = valid ? 1.0f : 0.0f;
    out[base + 1 * (size_t)N_PIX + j] = (float)q_idx;
    out[base + 2 * (size_t)N_PIX + j] = (float)qd;
    out[base + 3 * (size_t)N_PIX + j] = (float)qm;
    out[base + 4 * (size_t)N_PIX + j] = (float)pd;
    out[base + 5 * (size_t)N_PIX + j] = (float)pm;
}

extern "C" void kernel_launch(void* const* d_in, const int* in_sizes, int n_in,
                              void* d_out, int out_size, void* d_ws, size_t ws_size,
                              hipStream_t stream) {
    const float* Q = (const float*)d_in[0];
    const float* P = (const float*)d_in[1];
    float* out = (float*)d_out;

    unsigned long long* row_best = (unsigned long long*)d_ws;
    unsigned long long* col_best = row_best + N_PIX;
    float* invq = (float*)(col_best + N_PIX);
    float* invp = invq + N_PIX;

    hipMemsetAsync(d_ws, 0, 2 * N_PIX * sizeof(unsigned long long), stream);

    const size_t base_bytes = 2 * N_PIX * sizeof(unsigned long long) + 2 * N_PIX * sizeof(float);
    const size_t arr_u4 = (size_t)(CCH / 8) * N_PIX;  // 32 kb-rows x N uint4
    const size_t need = base_bytes + 4 * arr_u4 * sizeof(uint4);

    if (ws_size >= need) {
        uint4* qh = (uint4*)((char*)d_ws + base_bytes);
        uint4* ql = qh + arr_u4;
        uint4* ph = ql + arr_u4;
        uint4* pl = ph + arr_u4;

        prep_kernel<<<N_PIX / 64, 256, 0, stream>>>(Q, P, qh, ql, ph, pl, invq, invp);
        mfma_gemm_kernel<<<5184, 256, 0, stream>>>(qh, ql, ph, pl, invq, invp,
                                                   out, row_best, col_best);
    } else {
        // workspace too small for split arrays: proven legacy path
        norms_kernel<<<N_PIX / 256, 256, 0, stream>>>(Q, P, invq, invp);
        dim3 grid(N_PIX / BN, N_PIX / BM);
        gemm_kernel<<<grid, 256, 0, stream>>>(Q, P, invq, invp, out, row_best, col_best);
    }

    epilogue_kernel<<<N_PIX / 256, 256, 0, stream>>>(row_best, col_best, out);
}

// Round 3
// 467.885 us; speedup vs baseline: 2.0364x; 1.0370x over previous
//
#include <hip/hip_runtime.h>
#include <hip/hip_fp16.h>

#define N_PIX 9216
#define CCH 256
#define W_ 96
#define H_ 96
#define BM 128
#define BN 128
#define BK 16
#define TM 8
#define TN 8

typedef _Float16 half8_t __attribute__((ext_vector_type(8)));
typedef float f32x4_t __attribute__((ext_vector_type(4)));

// Monotone encoding: unsigned compare order == float compare order.
__device__ __forceinline__ unsigned int mono_enc(float f) {
    unsigned int u = __float_as_uint(f);
    return (u & 0x80000000u) ? ~u : (u | 0x80000000u);
}
__device__ __forceinline__ float mono_dec(unsigned int e) {
    return __uint_as_float((e & 0x80000000u) ? (e ^ 0x80000000u) : ~e);
}

// async global->LDS, 16B per lane; LDS dest is wave-uniform base + lane*16.
__device__ __forceinline__ void gload_lds16(const uint4* g, uint4* lds) {
    __builtin_amdgcn_global_load_lds(
        (const __attribute__((address_space(1))) unsigned int*)g,
        (__attribute__((address_space(3))) unsigned int*)lds, 16, 0, 0);
}

// ======================= legacy (fallback) path =======================

__global__ __launch_bounds__(256) void norms_kernel(const float* __restrict__ Q,
                                                    const float* __restrict__ P,
                                                    float* __restrict__ invq,
                                                    float* __restrict__ invp) {
    int n = blockIdx.x * blockDim.x + threadIdx.x;
    if (n >= N_PIX) return;
    float sq = 0.f, sp = 0.f;
    for (int c = 0; c < CCH; ++c) {
        float a = Q[(size_t)c * N_PIX + n];
        float b = P[(size_t)c * N_PIX + n];
        sq = fmaf(a, a, sq);
        sp = fmaf(b, b, sp);
    }
    invq[n] = 1.0f / sqrtf(sq);
    invp[n] = 1.0f / sqrtf(sp);
}

__device__ __forceinline__ int local_row(int ty, int i) {
    return (i < 4) ? (ty * 4 + i) : (64 + ty * 4 + (i - 4));
}
__device__ __forceinline__ int local_col(int tx, int j) {
    return (j < 4) ? (tx * 4 + j) : (64 + tx * 4 + (j - 4));
}

__global__ __launch_bounds__(256) void gemm_kernel(const float* __restrict__ Q,
                                                   const float* __restrict__ P,
                                                   const float* __restrict__ invq,
                                                   const float* __restrict__ invp,
                                                   float* __restrict__ sim,
                                                   unsigned long long* __restrict__ row_best,
                                                   unsigned long long* __restrict__ col_best) {
    __shared__ union SH {
        struct { float A[BK][BM]; float B[BK][BN]; } t;
        unsigned long long red[16][128];
    } sh;

    const int tid = threadIdx.x;
    const int tx = tid & 15;
    const int ty = tid >> 4;
    const int n0 = blockIdx.y * BM;
    const int m0 = blockIdx.x * BN;

    float acc[TM][TN];
#pragma unroll
    for (int i = 0; i < TM; ++i)
#pragma unroll
        for (int j = 0; j < TN; ++j) acc[i][j] = 0.f;

    for (int kk = 0; kk < CCH; kk += BK) {
#pragma unroll
        for (int rep = 0; rep < 2; ++rep) {
            int idx = tid + rep * 256;
            int row = idx >> 5;
            int c4  = idx & 31;
            float4 av = *(const float4*)&Q[(size_t)(kk + row) * N_PIX + n0 + c4 * 4];
            float4 bv = *(const float4*)&P[(size_t)(kk + row) * N_PIX + m0 + c4 * 4];
            *(float4*)&sh.t.A[row][c4 * 4] = av;
            *(float4*)&sh.t.B[row][c4 * 4] = bv;
        }
        __syncthreads();
#pragma unroll
        for (int k = 0; k < BK; ++k) {
            float a[TM], b[TN];
            *(float4*)&a[0] = *(const float4*)&sh.t.A[k][ty * 4];
            *(float4*)&a[4] = *(const float4*)&sh.t.A[k][ty * 4 + 64];
            *(float4*)&b[0] = *(const float4*)&sh.t.B[k][tx * 4];
            *(float4*)&b[4] = *(const float4*)&sh.t.B[k][tx * 4 + 64];
#pragma unroll
            for (int i = 0; i < TM; ++i)
#pragma unroll
                for (int j = 0; j < TN; ++j)
                    acc[i][j] = fmaf(a[i], b[j], acc[i][j]);
        }
        __syncthreads();
    }

    float iq[TM], ip[TN];
#pragma unroll
    for (int i = 0; i < TM; ++i) iq[i] = invq[n0 + local_row(ty, i)];
#pragma unroll
    for (int j = 0; j < TN; ++j) ip[j] = invp[m0 + local_col(tx, j)];
#pragma unroll
    for (int i = 0; i < TM; ++i)
#pragma unroll
        for (int j = 0; j < TN; ++j) acc[i][j] *= iq[i] * ip[j];

#pragma unroll
    for (int i = 0; i < TM; ++i) {
        int n = n0 + local_row(ty, i);
        float4 v0 = make_float4(acc[i][0], acc[i][1], acc[i][2], acc[i][3]);
        float4 v1 = make_float4(acc[i][4], acc[i][5], acc[i][6], acc[i][7]);
        float* dst = &sim[(size_t)n * N_PIX + m0];
        *(float4*)(dst + tx * 4) = v0;
        *(float4*)(dst + 64 + tx * 4) = v1;
    }

#pragma unroll
    for (int i = 0; i < TM; ++i) {
        float best = acc[i][0]; int bj = 0;
#pragma unroll
        for (int j = 1; j < TN; ++j)
            if (acc[i][j] > best) { best = acc[i][j]; bj = j; }
        unsigned int gcol = (unsigned int)(m0 + local_col(tx, bj));
        sh.red[tx][local_row(ty, i)] =
            ((unsigned long long)mono_enc(best) << 32) | (unsigned long long)(0xFFFFFFFFu - gcol);
    }
    __syncthreads();
    if (tid < 128) {
        unsigned long long best = sh.red[0][tid];
#pragma unroll
        for (int x = 1; x < 16; ++x) {
            unsigned long long v = sh.red[x][tid];
            if (v > best) best = v;
        }
        atomicMax(&row_best[n0 + tid], best);
    }
    __syncthreads();

#pragma unroll
    for (int j = 0; j < TN; ++j) {
        float best = acc[0][j]; int bi = 0;
#pragma unroll
        for (int i = 1; i < TM; ++i)
            if (acc[i][j] > best) { best = acc[i][j]; bi = i; }
        unsigned int grow = (unsigned int)(n0 + local_row(ty, bi));
        sh.red[ty][local_col(tx, j)] =
            ((unsigned long long)mono_enc(best) << 32) | (unsigned long long)(0xFFFFFFFFu - grow);
    }
    __syncthreads();
    if (tid < 128) {
        unsigned long long best = sh.red[0][tid];
#pragma unroll
        for (int x = 1; x < 16; ++x) {
            unsigned long long v = sh.red[x][tid];
            if (v > best) best = v;
        }
        atomicMax(&col_best[m0 + tid], best);
    }
}

// ======================= fast (MFMA) path =======================

__device__ __forceinline__ unsigned int pack_pair(float x, float y, float& rx, float& ry) {
    __half hx = __float2half(x), hy = __float2half(y);
    rx = x - __half2float(hx);
    ry = y - __half2float(hy);
    return (unsigned int)__half_as_ushort(hx) | ((unsigned int)__half_as_ushort(hy) << 16);
}

// Fused norms + fp16-split kernel. Output layout is FRAGMENT-MAJOR:
// for kb = dword-row/4 (0..31), array[kb*N_PIX + n] is a uint4 holding the
// 4 k-pair dwords (k = kb*8 .. kb*8+7) of pixel n == exactly one MFMA
// fragment register group, loadable with a single (dwordx4 | lds_dwordx4).
__global__ __launch_bounds__(256) void prep_kernel(const float* __restrict__ Q,
                                                   const float* __restrict__ P,
                                                   uint4* __restrict__ qh,
                                                   uint4* __restrict__ ql,
                                                   uint4* __restrict__ ph,
                                                   uint4* __restrict__ pl,
                                                   float* __restrict__ invq,
                                                   float* __restrict__ invp) {
    __shared__ float rq[4][64];
    __shared__ float rp[4][64];
    const int lane = threadIdx.x & 63;
    const int band = threadIdx.x >> 6;
    const int n = blockIdx.x * 64 + lane;
    float sq = 0.f, sp = 0.f;
    for (int kb = band * 8; kb < band * 8 + 8; ++kb) {
        float a[8], b[8];
#pragma unroll
        for (int t = 0; t < 8; ++t) {
            a[t] = Q[(size_t)(kb * 8 + t) * N_PIX + n];
            b[t] = P[(size_t)(kb * 8 + t) * N_PIX + n];
        }
#pragma unroll
        for (int t = 0; t < 8; ++t) {
            sq = fmaf(a[t], a[t], sq);
            sp = fmaf(b[t], b[t], sp);
        }
        uint4 vqh, vql, vph, vpl;
        unsigned int* uqh = (unsigned int*)&vqh;
        unsigned int* uql = (unsigned int*)&vql;
        unsigned int* uph = (unsigned int*)&vph;
        unsigned int* upl = (unsigned int*)&vpl;
#pragma unroll
        for (int j = 0; j < 4; ++j) {
            float r0, r1;
            uqh[j] = pack_pair(a[2 * j], a[2 * j + 1], r0, r1);
            uql[j] = (unsigned int)__half_as_ushort(__float2half(r0))
                   | ((unsigned int)__half_as_ushort(__float2half(r1)) << 16);
            uph[j] = pack_pair(b[2 * j], b[2 * j + 1], r0, r1);
            upl[j] = (unsigned int)__half_as_ushort(__float2half(r0))
                   | ((unsigned int)__half_as_ushort(__float2half(r1)) << 16);
        }
        size_t o = (size_t)kb * N_PIX + n;
        qh[o] = vqh; ql[o] = vql; ph[o] = vph; pl[o] = vpl;
    }
    rq[band][lane] = sq;
    rp[band][lane] = sp;
    __syncthreads();
    if (threadIdx.x < 64) {
        float tq = rq[0][lane] + rq[1][lane] + rq[2][lane] + rq[3][lane];
        float tp = rp[0][lane] + rp[1][lane] + rp[2][lane] + rp[3][lane];
        invq[n] = 1.0f / sqrtf(tq);
        invp[n] = 1.0f / sqrtf(tp);
    }
}

// 128x128 tile, 4 waves, wave = 64x64 = 4x4 fragments of 16x16x32 f16 MFMA.
// sim = Qn^T Pn via 2-term fp16 split: hi*hi + hi*lo + lo*hi.
// K-loop: double-buffered LDS staging via global_load_lds (width 16). Each
// K=32 step stages the block's unique 32 KB once (vs 64 KB of duplicated
// per-wave global fragment loads) -> L2 traffic halves and L1 stops
// thrashing; fragments come from ds_read_b128 (256 B runs, conflict-free).
__global__ __launch_bounds__(256, 2) void mfma_gemm_kernel(
        const uint4* __restrict__ QH, const uint4* __restrict__ QL,
        const uint4* __restrict__ PH, const uint4* __restrict__ PL,
        const float* __restrict__ invq, const float* __restrict__ invp,
        float* __restrict__ sim,
        unsigned long long* __restrict__ row_best,
        unsigned long long* __restrict__ col_best) {
    // Serpentine XCD swizzle: each XCD owns 9 by-panels; within it, walk
    // 8-wide bx-groups so the resident blocks/XCD touch an L2-fitting set.
    const unsigned int bid = blockIdx.x;
    const unsigned int xcd = bid & 7u;
    const unsigned int nbl = bid >> 3;           // 0..647
    const unsigned int gg  = nbl / 72u;          // 0..8  bx-group
    const unsigned int rr  = nbl % 72u;
    const unsigned int by  = xcd * 9u + (rr >> 3);   // 0..71
    const unsigned int bx  = gg * 8u + (rr & 7u);    // 0..71

    const int tid = threadIdx.x;
    const int l  = tid & 63;
    const int w  = tid >> 6;
    const int rl = l & 15;   // fragment row (A) / col (B,D)
    const int kg = l >> 4;   // k-group; also D-row group
    const int n0 = (int)by * 128;                  // block row base
    const int m0 = (int)bx * 128;                  // block col base
    const int r0 = n0 + (w >> 1) * 64;             // wave row base
    const int c0 = m0 + (w & 1) * 64;              // wave col base

    // stage: [dbuf][arr Ah,Al,Bh,Bl][kb 0..3][pixel 0..127] = 64 KB,
    // union'd with the per-wave store-transpose buffer (used after the loop).
    __shared__ union SH2 {
        uint4 stage[2][4][4][128];
        float st[4][16][68];
    } sh;

    const f32x4_t zero4 = {0.f, 0.f, 0.f, 0.f};
    f32x4_t acc[4][4];
#pragma unroll
    for (int i = 0; i < 4; ++i)
#pragma unroll
        for (int j = 0; j < 4; ++j) acc[i][j] = zero4;

    // wave w stages array w from global (A arrays at n0, B arrays at m0)
    const uint4* gsrc = (w == 0) ? (QH + n0) : (w == 1) ? (QL + n0)
                      : (w == 2) ? (PH + m0) : (PL + m0);

    // prologue: stage step 0 into buffer 0
#pragma unroll
    for (int kb = 0; kb < 4; ++kb)
#pragma unroll
        for (int h = 0; h < 2; ++h)
            gload_lds16(gsrc + (size_t)kb * N_PIX + h * 64 + l,
                        &sh.stage[0][w][kb][h * 64]);
    asm volatile("s_waitcnt vmcnt(0)" ::: "memory");
    __syncthreads();

    const int ar = (w >> 1) * 64 + rl;
    const int br = (w & 1) * 64 + rl;

    for (int s = 0; s < 8; ++s) {
        const int cur = s & 1;
        if (s < 7) {
            const uint4* gs = gsrc + (size_t)((s + 1) * 4) * N_PIX;
#pragma unroll
            for (int kb = 0; kb < 4; ++kb)
#pragma unroll
                for (int h = 0; h < 2; ++h)
                    gload_lds16(gs + (size_t)kb * N_PIX + h * 64 + l,
                                &sh.stage[cur ^ 1][w][kb][h * 64]);
        }
        half8_t ah[4], al4[4], bh4[4], bl4[4];
#pragma unroll
        for (int f = 0; f < 4; ++f) {
            ah[f]  = *(const half8_t*)&sh.stage[cur][0][kg][ar + f * 16];
            al4[f] = *(const half8_t*)&sh.stage[cur][1][kg][ar + f * 16];
            bh4[f] = *(const half8_t*)&sh.stage[cur][2][kg][br + f * 16];
            bl4[f] = *(const half8_t*)&sh.stage[cur][3][kg][br + f * 16];
        }
#pragma unroll
        for (int fr = 0; fr < 4; ++fr)
#pragma unroll
            for (int fc = 0; fc < 4; ++fc) {
                acc[fr][fc] = __builtin_amdgcn_mfma_f32_16x16x32_f16(ah[fr],  bh4[fc], acc[fr][fc], 0, 0, 0);
                acc[fr][fc] = __builtin_amdgcn_mfma_f32_16x16x32_f16(ah[fr],  bl4[fc], acc[fr][fc], 0, 0, 0);
                acc[fr][fc] = __builtin_amdgcn_mfma_f32_16x16x32_f16(al4[fr], bh4[fc], acc[fr][fc], 0, 0, 0);
            }
        asm volatile("s_waitcnt vmcnt(0)" ::: "memory");
        __syncthreads();
    }

    // ---- scale by inverse norms (in-register) ----
    float iq[4][4];
#pragma unroll
    for (int fr = 0; fr < 4; ++fr) {
        const float4 v = *(const float4*)&invq[r0 + fr * 16 + kg * 4];
        iq[fr][0] = v.x; iq[fr][1] = v.y; iq[fr][2] = v.z; iq[fr][3] = v.w;
    }
    float ip[4];
#pragma unroll
    for (int fc = 0; fc < 4; ++fc) ip[fc] = invp[c0 + fc * 16 + rl];

#pragma unroll
    for (int fr = 0; fr < 4; ++fr)
#pragma unroll
        for (int fc = 0; fc < 4; ++fc)
#pragma unroll
            for (int j = 0; j < 4; ++j)
                acc[fr][fc][j] *= iq[fr][j] * ip[fc];

    // ---- row bests: reduce over this wave's 64 cols (fc in-lane, rl x-lane) ----
#pragma unroll
    for (int fr = 0; fr < 4; ++fr)
#pragma unroll
        for (int j = 0; j < 4; ++j) {
            float best = acc[fr][0][j];
            int bf = 0;
#pragma unroll
            for (int fc = 1; fc < 4; ++fc)
                if (acc[fr][fc][j] > best) { best = acc[fr][fc][j]; bf = fc; }
            const unsigned int gcol = (unsigned int)(c0 + bf * 16 + rl);
            unsigned long long key = ((unsigned long long)mono_enc(best) << 32)
                                   | (unsigned long long)(0xFFFFFFFFu - gcol);
#pragma unroll
            for (int m = 1; m < 16; m <<= 1) {
                unsigned long long o = __shfl_xor(key, m, 64);
                if (o > key) key = o;
            }
            if (rl == 0)
                atomicMax(&row_best[r0 + fr * 16 + kg * 4 + j], key);
        }

    // ---- col bests: reduce over this wave's 64 rows (fr,j in-lane, kg x-lane) ----
#pragma unroll
    for (int fc = 0; fc < 4; ++fc) {
        float best = acc[0][fc][0];
        unsigned int brow = (unsigned int)(r0 + kg * 4);
#pragma unroll
        for (int fr = 0; fr < 4; ++fr)
#pragma unroll
            for (int j = 0; j < 4; ++j) {
                float v = acc[fr][fc][j];  // rows scanned in increasing order
                unsigned int rr2 = (unsigned int)(r0 + fr * 16 + kg * 4 + j);
                if (v > best) { best = v; brow = rr2; }
            }
        unsigned long long key = ((unsigned long long)mono_enc(best) << 32)
                               | (unsigned long long)(0xFFFFFFFFu - brow);
#pragma unroll
        for (int m = 16; m < 64; m <<= 1) {
            unsigned long long o = __shfl_xor(key, m, 64);
            if (o > key) key = o;
        }
        if (kg == 0)
            atomicMax(&col_best[c0 + fc * 16 + rl], key);
    }

    // ---- sim stores via per-wave LDS transpose: full-line writes ----
    // (stage buffers are dead by now: vmcnt(0)+barrier ended the loop)
#pragma unroll
    for (int fr = 0; fr < 4; ++fr) {
        asm volatile("s_waitcnt lgkmcnt(0)" ::: "memory");  // prior fr's reads done
#pragma unroll
        for (int fc = 0; fc < 4; ++fc)
#pragma unroll
            for (int j = 0; j < 4; ++j)
                sh.st[w][kg * 4 + j][fc * 16 + rl] = acc[fr][fc][j];
        asm volatile("s_waitcnt lgkmcnt(0)" ::: "memory");  // writes visible to wave
#pragma unroll
        for (int pass = 0; pass < 4; ++pass) {
            const int rowL = pass * 4 + kg;
            const f32x4_t v = *(const f32x4_t*)&sh.st[w][rowL][rl * 4];
            const int gr = r0 + fr * 16 + rowL;
            // 16 lanes (rl) x 16 B contiguous per row = 256 B runs, 4 rows/inst
            __builtin_nontemporal_store(v, (f32x4_t*)(sim + (size_t)gr * N_PIX + c0 + rl * 4));
        }
    }
}

// ======================= shared epilogue =======================

__global__ __launch_bounds__(256) void epilogue_kernel(const unsigned long long* __restrict__ row_best,
                                                       const unsigned long long* __restrict__ col_best,
                                                       float* __restrict__ out) {
    int j = blockIdx.x * blockDim.x + threadIdx.x;
    if (j >= N_PIX) return;
    unsigned long long cb = col_best[j];
    unsigned int q_idx = 0xFFFFFFFFu - (unsigned int)(cb & 0xFFFFFFFFull);
    float simval = mono_dec((unsigned int)(cb >> 32));
    unsigned long long rb = row_best[q_idx];
    unsigned int rm = 0xFFFFFFFFu - (unsigned int)(rb & 0xFFFFFFFFull);
    bool mutual = (rm == (unsigned int)j) && (simval > 0.9f);
    int qd = (int)(q_idx / W_), qm = (int)(q_idx % W_);
    int pd = j / W_, pm = j % W_;
    bool valid = mutual && (qd + 1 < H_) && (pd + 1 < H_);
    size_t base = (size_t)N_PIX * N_PIX;
    out[base + 0 * (size_t)N_PIX + j] = valid ? 1.0f : 0.0f;
    out[base + 1 * (size_t)N_PIX + j] = (float)q_idx;
    out[base + 2 * (size_t)N_PIX + j] = (float)qd;
    out[base + 3 * (size_t)N_PIX + j] = (float)qm;
    out[base + 4 * (size_t)N_PIX + j] = (float)pd;
    out[base + 5 * (size_t)N_PIX + j] = (float)pm;
}

extern "C" void kernel_launch(void* const* d_in, const int* in_sizes, int n_in,
                              void* d_out, int out_size, void* d_ws, size_t ws_size,
                              hipStream_t stream) {
    const float* Q = (const float*)d_in[0];
    const float* P = (const float*)d_in[1];
    float* out = (float*)d_out;

    unsigned long long* row_best = (unsigned long long*)d_ws;
    unsigned long long* col_best = row_best + N_PIX;
    float* invq = (float*)(col_best + N_PIX);
    float* invp = invq + N_PIX;

    hipMemsetAsync(d_ws, 0, 2 * N_PIX * sizeof(unsigned long long), stream);

    const size_t base_bytes = 2 * N_PIX * sizeof(unsigned long long) + 2 * N_PIX * sizeof(float);
    const size_t arr_u4 = (size_t)(CCH / 8) * N_PIX;  // 32 kb-rows x N uint4
    const size_t need = base_bytes + 4 * arr_u4 * sizeof(uint4);

    if (ws_size >= need) {
        uint4* qh = (uint4*)((char*)d_ws + base_bytes);
        uint4* ql = qh + arr_u4;
        uint4* ph = ql + arr_u4;
        uint4* pl = ph + arr_u4;

        prep_kernel<<<N_PIX / 64, 256, 0, stream>>>(Q, P, qh, ql, ph, pl, invq, invp);
        mfma_gemm_kernel<<<5184, 256, 0, stream>>>(qh, ql, ph, pl, invq, invp,
                                                   out, row_best, col_best);
    } else {
        // workspace too small for split arrays: proven legacy path
        norms_kernel<<<N_PIX / 256, 256, 0, stream>>>(Q, P, invq, invp);
        dim3 grid(N_PIX / BN, N_PIX / BM);
        gemm_kernel<<<grid, 256, 0, stream>>>(Q, P, invq, invp, out, row_best, col_best);
    }

    epilogue_kernel<<<N_PIX / 256, 256, 0, stream>>>(row_best, col_best, out);
}